// Round 4
// baseline (446.936 us; speedup 1.0000x reference)
//
#include <hip/hip_runtime.h>
#include <hip/hip_bf16.h>
#include <math.h>

typedef short short8 __attribute__((ext_vector_type(8)));
typedef float floatx4 __attribute__((ext_vector_type(4)));
typedef int   intx4  __attribute__((ext_vector_type(4)));

#define D 128
#define Q 2500
#define QPAD 2560
#define NK 10080
#define NKPAD 10112
#define SPLITS 21
#define CPS 15  // chunks of 32 k per split; 21*15*32 = 10080
// padded strides (avoid 4096B channel alignment)
#define OPS 163904   // u32 per split for OpartU (163840 + 64)
#define LPS 10304    // f32 per split for lpart (10240 + 64)
// 1/sqrt(32) * log2(e)
#define QSCALE 0.25501268426834347f
#define NEGBIG -3.0e38f

__device__ __forceinline__ unsigned short f2bf(float f) {
    unsigned u = __float_as_uint(f);
    unsigned r = (u + 0x7fffu + ((u >> 16) & 1u)) >> 16;
    return (unsigned short)r;
}
__device__ __forceinline__ unsigned pack2bf(float lo, float hi) {
    unsigned u0 = __float_as_uint(lo) + 0x8000u;
    unsigned u1 = __float_as_uint(hi) + 0x8000u;
    return (u0 >> 16) | (u1 & 0xffff0000u);
}
__device__ __forceinline__ float bflo(unsigned u) { return __uint_as_float(u << 16); }
__device__ __forceinline__ float bfhi(unsigned u) { return __uint_as_float(u & 0xffff0000u); }

// ---------- weight convert: fp32 [in][out] -> bf16 transposed [out][in] ----------
__global__ void wcvt_kernel(const float* __restrict__ wq, const float* __restrict__ wk,
                            const float* __restrict__ wv, const float* __restrict__ wp,
                            const float* __restrict__ w1, const float* __restrict__ w2,
                            unsigned short* __restrict__ wqT, unsigned short* __restrict__ wkT,
                            unsigned short* __restrict__ wvT, unsigned short* __restrict__ wpT,
                            unsigned short* __restrict__ w1T, unsigned short* __restrict__ w2T) {
    int idx = blockIdx.x * 256 + threadIdx.x;  // 131072 total
    if (idx < 49152) {
        int m = idx >> 14;
        int local = idx & 16383;
        int n = local >> 7, kk = local & 127;
        const float* w = (m == 0) ? wq : ((m == 1) ? wk : wv);
        unsigned short* o = (m == 0) ? wqT : ((m == 1) ? wkT : wvT);
        o[local] = f2bf(w[kk * 128 + n]);
    } else if (idx < 65536) {
        int local = idx - 49152;
        int n = local >> 7, kk = local & 127;
        wpT[local] = f2bf(wp[kk * 128 + n]);
    } else if (idx < 98304) {
        int local = idx - 65536;
        int n = local >> 7, kk = local & 127;
        w1T[local] = f2bf(w1[kk * 256 + n]);
    } else {
        int local = idx - 98304;
        int n = local >> 8, kk = local & 255;
        w2T[local] = f2bf(w2[kk * 128 + n]);
    }
}

// ---------- LayerNorm: 16 positions x 128 d per block, coalesced ----------
__global__ __launch_bounds__(256) void ln_kernel(
    const float* __restrict__ qi, const float* __restrict__ ki, const float* __restrict__ vi,
    const float* __restrict__ qw, const float* __restrict__ qb,
    const float* __restrict__ kw, const float* __restrict__ kb,
    const float* __restrict__ vw, const float* __restrict__ vb,
    unsigned short* __restrict__ xq, unsigned short* __restrict__ xk,
    unsigned short* __restrict__ xv) {
    __shared__ float lds[16 * 132];
    int bid = blockIdx.x, t = threadIdx.x;
    const float* src; unsigned short* dst; const float *g, *b;
    int S, valid;
    if (bid < 157) {
        int p0 = bid * 16;
        src = qi + p0; S = Q; dst = xq + p0 * D; g = qw; b = qb;
        valid = Q - p0; if (valid > 16) valid = 16;
    } else if (bid < 787) {
        int tt = bid - 157;
        int n = tt / 105, r = (tt - n * 105) * 16;
        src = ki + (size_t)(n * 128) * 1680 + r; S = 1680;
        dst = xk + (n * 1680 + r) * D; g = kw; b = kb; valid = 16;
    } else {
        int tt = bid - 787;
        int n = tt / 105, r = (tt - n * 105) * 16;
        src = vi + (size_t)(n * 128) * 1680 + r; S = 1680;
        dst = xv + (n * 1680 + r) * D; g = vw; b = vb; valid = 16;
    }
    int c4 = t & 3, d = t >> 2;
    floatx4 fa = {0.f, 0.f, 0.f, 0.f}, fb = {0.f, 0.f, 0.f, 0.f};
    if (c4 * 4 < valid) {
        fa = *(const floatx4*)(src + d * S + c4 * 4);
        fb = *(const floatx4*)(src + (d + 64) * S + c4 * 4);
    }
    #pragma unroll
    for (int j = 0; j < 4; j++) {
        lds[(c4 * 4 + j) * 132 + d] = fa[j];
        lds[(c4 * 4 + j) * 132 + d + 64] = fb[j];
    }
    __syncthreads();
    int lane = t & 63, wv = t >> 6;
    int pos = wv * 4 + (lane >> 4), l15 = lane & 15;
    floatx4 xa = *(const floatx4*)(&lds[pos * 132 + l15 * 8]);
    floatx4 xb = *(const floatx4*)(&lds[pos * 132 + l15 * 8 + 4]);
    float s = 0.f, ss = 0.f;
    #pragma unroll
    for (int j = 0; j < 4; j++) { s += xa[j] + xb[j]; ss += xa[j] * xa[j] + xb[j] * xb[j]; }
    #pragma unroll
    for (int m = 1; m <= 8; m <<= 1) { s += __shfl_xor(s, m, 64); ss += __shfl_xor(ss, m, 64); }
    float mean = s * (1.0f / 128.0f);
    float var = ss * (1.0f / 128.0f) - mean * mean;
    float rstd = rsqrtf(var + 1e-5f);
    floatx4 g0 = *(const floatx4*)(g + l15 * 8), g1 = *(const floatx4*)(g + l15 * 8 + 4);
    floatx4 b0 = *(const floatx4*)(b + l15 * 8), b1 = *(const floatx4*)(b + l15 * 8 + 4);
    short8 o;
    #pragma unroll
    for (int j = 0; j < 4; j++) {
        o[j] = (short)f2bf((xa[j] - mean) * rstd * g0[j] + b0[j]);
        o[4 + j] = (short)f2bf((xb[j] - mean) * rstd * g1[j] + b1[j]);
    }
    if (pos < valid) *(short8*)(dst + pos * D + l15 * 8) = o;
}

// ---------- Projection GEMM, vectorized weights; V written transposed ----------
__global__ __launch_bounds__(256) void proj_kernel(
    const unsigned short* __restrict__ xq, const unsigned short* __restrict__ xk,
    const unsigned short* __restrict__ xv,
    const unsigned short* __restrict__ wqT, const unsigned short* __restrict__ wkT,
    const unsigned short* __restrict__ wvT,
    const float* __restrict__ bq, const float* __restrict__ bk, const float* __restrict__ bv,
    unsigned short* __restrict__ qh, unsigned short* __restrict__ kh,
    unsigned short* __restrict__ vhT) {
    __shared__ short vlds[128 * 72];
    int bid = blockIdx.x;
    const unsigned short *src, *wT; const float* bias; int mb, mode; float scale;
    if (bid < 40)       { mode = 0; src = xq; wT = wqT; bias = bq; mb = bid * 64; scale = QSCALE; }
    else if (bid < 198) { mode = 1; src = xk; wT = wkT; bias = bk; mb = (bid - 40) * 64; scale = 1.0f; }
    else                { mode = 2; src = xv; wT = wvT; bias = bv; mb = (bid - 198) * 64; scale = 1.0f; }
    int t = threadIdx.x, wave = t >> 6, lane = t & 63;
    int l15 = lane & 15, quad = lane >> 4;
    int m0 = mb + wave * 16;
    floatx4 acc[8];
    #pragma unroll
    for (int i = 0; i < 8; i++) acc[i] = (floatx4){0.f, 0.f, 0.f, 0.f};
    #pragma unroll
    for (int kf = 0; kf < 4; kf++) {
        short8 A = *(const short8*)(src + (m0 + l15) * D + kf * 32 + quad * 8);
        #pragma unroll
        for (int nt = 0; nt < 8; nt++) {
            short8 Bv = *(const short8*)(wT + (nt * 16 + l15) * D + kf * 32 + quad * 8);
            acc[nt] = __builtin_amdgcn_mfma_f32_16x16x32_bf16(A, Bv, acc[nt], 0, 0, 0);
        }
    }
    if (mode != 2) {
        unsigned short* dst = (mode == 0) ? qh : kh;
        #pragma unroll
        for (int nt = 0; nt < 8; nt++) {
            float bb = bias[nt * 16 + l15];
            #pragma unroll
            for (int r = 0; r < 4; r++)
                dst[(m0 + quad * 4 + r) * D + nt * 16 + l15] = f2bf((acc[nt][r] + bb) * scale);
        }
    } else {
        #pragma unroll
        for (int nt = 0; nt < 8; nt++) {
            float bb = bias[nt * 16 + l15];
            #pragma unroll
            for (int r = 0; r < 4; r++)
                vlds[(nt * 16 + l15) * 72 + (wave * 16 + quad * 4 + r)] =
                    (short)f2bf(acc[nt][r] + bb);
        }
        __syncthreads();
        int pr = t & 31, dd = t >> 5;
        int sub = pr >> 4, i = pr & 15;
        #pragma unroll
        for (int pass = 0; pass < 16; pass++) {
            int d = pass * 8 + dd;
            unsigned lo = (unsigned short)vlds[d * 72 + sub * 32 + i];
            unsigned hi = (unsigned short)vlds[d * 72 + sub * 32 + 16 + i];
            *(unsigned*)(vhT + (size_t)d * NKPAD + mb + sub * 32 + 2 * i) = lo | (hi << 16);
        }
    }
}

// ---------- Fused attention v4: S^T layout, zero LDS, shuffle-based P transpose ----------
__global__ __launch_bounds__(256, 3) void attn_kernel(
    const unsigned short* __restrict__ qh, const unsigned short* __restrict__ kh,
    const unsigned short* __restrict__ vhT,
    const float* __restrict__ Wl, const int* __restrict__ vis,
    unsigned* __restrict__ OpartU, float* __restrict__ lpart) {
    int bid = blockIdx.x;
    int split = bid % SPLITS, qt4 = bid / SPLITS;
    int lane = threadIdx.x & 63, wave = threadIdx.x >> 6;
    int l15 = lane & 15, quad = lane >> 4;
    int qb = (qt4 * 4 + wave) * 16;
    int k00 = split * (CPS * 32);

    // Q as B-operand (loop-invariant)
    short8 qB[4];
    #pragma unroll
    for (int h = 0; h < 4; h++)
        qB[h] = *(const short8*)(qh + (qb + l15) * D + h * 32 + quad * 8);

    // W/vis: each lane covers q = qb+l15, k = k0 + tile*16 + quad*4 + r
    int wrow = qb + l15; if (wrow >= Q) wrow = Q - 1;
    const float* wp = Wl + (size_t)wrow * NK + k00 + quad * 4;
    const int*   vp = vis + (size_t)wrow * NK + k00 + quad * 4;

    const floatx4 zf = {0.f, 0.f, 0.f, 0.f};
    floatx4 O[4][2];
    float lacc[4];
    #pragma unroll
    for (int h = 0; h < 4; h++) { O[h][0] = zf; O[h][1] = zf; lacc[h] = 0.f; }

    // shuffle indices for P^T C->B transform (uniform per quad, hoisted)
    int sidx[4];
    #pragma unroll
    for (int jj = 0; jj < 4; jj++)
        sidx[jj] = l15 + 16 * ((quad & 1) * 2 + (jj >> 1));
    bool hiTile = quad >= 2;

    // prologue: chunk 0 W/vis
    floatx4 wc0 = *(const floatx4*)(wp);
    floatx4 wc1 = *(const floatx4*)(wp + 16);
    intx4   vc0 = *(const intx4*)(vp);
    intx4   vc1 = *(const intx4*)(vp + 16);

    #pragma unroll 1
    for (int c = 0; c < CPS; c++) {
        int k0 = k00 + c * 32;
        floatx4 wn0, wn1; intx4 vn0, vn1;
        if (c + 1 < CPS) {  // prefetch next chunk's HBM stream
            wn0 = *(const floatx4*)(wp + (c + 1) * 32);
            wn1 = *(const floatx4*)(wp + (c + 1) * 32 + 16);
            vn0 = *(const intx4*)(vp + (c + 1) * 32);
            vn1 = *(const intx4*)(vp + (c + 1) * 32 + 16);
        }
        // in-register mask/weight: L = S*a2 + b2
        float a2[8], b2[8];
        #pragma unroll
        for (int r = 0; r < 4; r++) {
            a2[r]     = vc0[r] ? wc0[r] : 0.f;
            b2[r]     = vc0[r] ? 0.f : wc0[r] * NEGBIG;
            a2[4 + r] = vc1[r] ? wc1[r] : 0.f;
            b2[4 + r] = vc1[r] ? 0.f : wc1[r] * NEGBIG;
        }
        #pragma unroll
        for (int h = 0; h < 4; h++) {
            short8 kA0 = *(const short8*)(kh + (k0 + l15) * D + h * 32 + quad * 8);
            short8 kA1 = *(const short8*)(kh + (k0 + 16 + l15) * D + h * 32 + quad * 8);
            // S^T[k][q]: lane holds k = quad*4+r (tile0), 16+quad*4+r (tile1), q = l15
            floatx4 S0 = __builtin_amdgcn_mfma_f32_16x16x32_bf16(kA0, qB[h], zf, 0, 0, 0);
            floatx4 S1 = __builtin_amdgcn_mfma_f32_16x16x32_bf16(kA1, qB[h], zf, 0, 0, 0);
            float p0[4], p1[4];
            #pragma unroll
            for (int r = 0; r < 4; r++) {
                p0[r] = exp2f(S0[r] * a2[r] + b2[r]);
                p1[r] = exp2f(S1[r] * a2[4 + r] + b2[4 + r]);
                lacc[h] += p0[r] + p1[r];
            }
            unsigned PP0[2] = {pack2bf(p0[0], p0[1]), pack2bf(p0[2], p0[3])};
            unsigned PP1[2] = {pack2bf(p1[0], p1[1]), pack2bf(p1[2], p1[3])};
            // P^T as B-operand: 8 bpermutes of packed pairs + 4 selects
            union { unsigned u[4]; short8 s; } pb;
            #pragma unroll
            for (int jj = 0; jj < 4; jj++) {
                unsigned s0 = (unsigned)__shfl((int)PP0[jj & 1], sidx[jj], 64);
                unsigned s1 = (unsigned)__shfl((int)PP1[jj & 1], sidx[jj], 64);
                pb.u[jj] = hiTile ? s1 : s0;
            }
            short8 vA0 = *(const short8*)(vhT + (size_t)(h * 32 + l15) * NKPAD + k0 + quad * 8);
            short8 vA1 = *(const short8*)(vhT + (size_t)(h * 32 + 16 + l15) * NKPAD + k0 + quad * 8);
            O[h][0] = __builtin_amdgcn_mfma_f32_16x16x32_bf16(vA0, pb.s, O[h][0], 0, 0, 0);
            O[h][1] = __builtin_amdgcn_mfma_f32_16x16x32_bf16(vA1, pb.s, O[h][1], 0, 0, 0);
        }
        wc0 = wn0; wc1 = wn1; vc0 = vn0; vc1 = vn1;
    }

    int row = qb + l15;
    #pragma unroll
    for (int h = 0; h < 4; h++) {
        float lv = lacc[h];
        lv += __shfl_xor(lv, 16, 64);
        lv += __shfl_xor(lv, 32, 64);
        if (quad == 0) lpart[(size_t)split * LPS + row * 4 + h] = lv;
        #pragma unroll
        for (int tl = 0; tl < 2; tl++) {
            // lane holds O^T[d = h*32 + tl*16 + quad*4 + r][q = row]; slot = d_local/2
            uint2 o2;
            o2.x = pack2bf(O[h][tl][0], O[h][tl][1]);
            o2.y = pack2bf(O[h][tl][2], O[h][tl][3]);
            *(uint2*)(OpartU + (size_t)split * OPS + ((size_t)row * 4 + h) * 16 + tl * 8 + quad * 2) = o2;
        }
    }
}

// ---------- l-sum inverse ----------
__global__ void linv_kernel(const float* __restrict__ lpart, float* __restrict__ linv) {
    int i = blockIdx.x * 256 + threadIdx.x;  // 10240
    float s = 0.f;
    #pragma unroll
    for (int sp = 0; sp < SPLITS; sp++) s += lpart[(size_t)sp * LPS + i];
    linv[i] = 1.0f / fmaxf(s, 1e-30f);
}

// ---------- combine splits -> A1 (bf16, plain d layout) ----------
__global__ void combine_kernel(const unsigned* __restrict__ OpartU,
                               const float* __restrict__ linv,
                               unsigned* __restrict__ A1u) {
    int idx = blockIdx.x * 256 + threadIdx.x;  // grid 640 -> 163840 u32
    float lo = 0.f, hi = 0.f;
    #pragma unroll
    for (int sp = 0; sp < SPLITS; sp++) {
        unsigned u = OpartU[(size_t)sp * OPS + idx];
        lo += bflo(u);
        hi += bfhi(u);
    }
    float inv = linv[idx >> 4];
    A1u[idx] = pack2bf(lo * inv, hi * inv);
}

// ---------- MLP epilogue: wp + skip + preLN + MLP(gelu) + postLN + transpose ----------
__global__ __launch_bounds__(256) void mlp_kernel(
    const unsigned short* __restrict__ A1s, const unsigned short* __restrict__ wpT,
    const float* __restrict__ bp, const float* __restrict__ skip,
    const float* __restrict__ pre_w, const float* __restrict__ pre_b,
    const unsigned short* __restrict__ w1T, const float* __restrict__ b1,
    const unsigned short* __restrict__ w2T, const float* __restrict__ b2,
    const float* __restrict__ post_w, const float* __restrict__ post_b,
    float* __restrict__ out) {
    __shared__ __align__(16) char smem[51200];
    short* Z1 = (short*)smem;              // [64][136]
    short* H1 = (short*)(smem + 17408);    // [64][264]
    float* Zout = (float*)smem;            // [128][65] overlay after barrier

    int qb = blockIdx.x * 64;
    int t = threadIdx.x, wave = t >> 6, lane = t & 63;
    int l15 = lane & 15, quad = lane >> 4;
    int m0 = wave * 16;

    // G1: Z = A1 @ wp
    floatx4 z[8];
    #pragma unroll
    for (int i = 0; i < 8; i++) z[i] = (floatx4){0.f, 0.f, 0.f, 0.f};
    #pragma unroll
    for (int kf = 0; kf < 4; kf++) {
        short8 A = *(const short8*)(A1s + (qb + m0 + l15) * D + kf * 32 + quad * 8);
        #pragma unroll
        for (int nt = 0; nt < 8; nt++) {
            short8 Bv = *(const short8*)(wpT + (nt * 16 + l15) * D + kf * 32 + quad * 8);
            z[nt] = __builtin_amdgcn_mfma_f32_16x16x32_bf16(A, Bv, z[nt], 0, 0, 0);
        }
    }
    float Zv[8][4];
    #pragma unroll
    for (int nt = 0; nt < 8; nt++) {
        int n = nt * 16 + l15;
        float bb = bp[n];
        #pragma unroll
        for (int r = 0; r < 4; r++) {
            int q = qb + m0 + quad * 4 + r;
            int qc = q < Q ? q : (Q - 1);
            Zv[nt][r] = z[nt][r] + bb + skip[n * Q + qc];
        }
    }
    // pre-LN
    float Zn[8][4];
    {
        #pragma unroll
        for (int r = 0; r < 4; r++) {
            float s1 = 0.f, s2 = 0.f;
            #pragma unroll
            for (int nt = 0; nt < 8; nt++) { s1 += Zv[nt][r]; s2 += Zv[nt][r] * Zv[nt][r]; }
            #pragma unroll
            for (int m = 1; m <= 8; m <<= 1) { s1 += __shfl_xor(s1, m, 64); s2 += __shfl_xor(s2, m, 64); }
            float mean = s1 * (1.0f / 128.0f);
            float var = s2 * (1.0f / 128.0f) - mean * mean;
            float rstd = rsqrtf(var + 1e-5f);
            #pragma unroll
            for (int nt = 0; nt < 8; nt++) Zn[nt][r] = (Zv[nt][r] - mean) * rstd;
        }
        #pragma unroll
        for (int nt = 0; nt < 8; nt++) {
            int n = nt * 16 + l15;
            float g = pre_w[n], be = pre_b[n];
            #pragma unroll
            for (int r = 0; r < 4; r++) {
                Zn[nt][r] = Zn[nt][r] * g + be;
                Z1[(m0 + quad * 4 + r) * 136 + n] = (short)f2bf(Zn[nt][r]);
            }
        }
    }
    // G2: H = gelu(Z1 @ w1 + b1)
    {
        floatx4 h2[16];
        #pragma unroll
        for (int i = 0; i < 16; i++) h2[i] = (floatx4){0.f, 0.f, 0.f, 0.f};
        #pragma unroll
        for (int kf = 0; kf < 4; kf++) {
            short8 A = *(const short8*)(Z1 + (m0 + l15) * 136 + kf * 32 + quad * 8);
            #pragma unroll
            for (int nt = 0; nt < 16; nt++) {
                short8 Bv = *(const short8*)(w1T + (nt * 16 + l15) * D + kf * 32 + quad * 8);
                h2[nt] = __builtin_amdgcn_mfma_f32_16x16x32_bf16(A, Bv, h2[nt], 0, 0, 0);
            }
        }
        #pragma unroll
        for (int nt = 0; nt < 16; nt++) {
            int n = nt * 16 + l15;
            float bb = b1[n];
            #pragma unroll
            for (int r = 0; r < 4; r++) {
                float x = h2[nt][r] + bb;
                float gl = 0.5f * x * (1.0f + erff(x * 0.70710678118654752f));
                H1[(m0 + quad * 4 + r) * 264 + n] = (short)f2bf(gl);
            }
        }
    }
    // G3: R = H1 @ w2 + b2; Z2 = Zn + R
    floatx4 o3[8];
    #pragma unroll
    for (int i = 0; i < 8; i++) o3[i] = (floatx4){0.f, 0.f, 0.f, 0.f};
    #pragma unroll
    for (int kf = 0; kf < 8; kf++) {
        short8 A = *(const short8*)(H1 + (m0 + l15) * 264 + kf * 32 + quad * 8);
        #pragma unroll
        for (int nt = 0; nt < 8; nt++) {
            short8 Bv = *(const short8*)(w2T + (nt * 16 + l15) * 256 + kf * 32 + quad * 8);
            o3[nt] = __builtin_amdgcn_mfma_f32_16x16x32_bf16(A, Bv, o3[nt], 0, 0, 0);
        }
    }
    float Z2[8][4];
    #pragma unroll
    for (int nt = 0; nt < 8; nt++) {
        int n = nt * 16 + l15;
        float bb = b2[n];
        #pragma unroll
        for (int r = 0; r < 4; r++) Z2[nt][r] = Zn[nt][r] + o3[nt][r] + bb;
    }
    // post-LN
    float Zo[8][4];
    {
        #pragma unroll
        for (int r = 0; r < 4; r++) {
            float s1 = 0.f, s2 = 0.f;
            #pragma unroll
            for (int nt = 0; nt < 8; nt++) { s1 += Z2[nt][r]; s2 += Z2[nt][r] * Z2[nt][r]; }
            #pragma unroll
            for (int m = 1; m <= 8; m <<= 1) { s1 += __shfl_xor(s1, m, 64); s2 += __shfl_xor(s2, m, 64); }
            float mean = s1 * (1.0f / 128.0f);
            float var = s2 * (1.0f / 128.0f) - mean * mean;
            float rstd = rsqrtf(var + 1e-5f);
            #pragma unroll
            for (int nt = 0; nt < 8; nt++) Zo[nt][r] = (Z2[nt][r] - mean) * rstd;
        }
        #pragma unroll
        for (int nt = 0; nt < 8; nt++) {
            int n = nt * 16 + l15;
            float g = post_w[n], be = post_b[n];
            #pragma unroll
            for (int r = 0; r < 4; r++) Zo[nt][r] = Zo[nt][r] * g + be;
        }
    }
    __syncthreads();
    #pragma unroll
    for (int nt = 0; nt < 8; nt++)
        #pragma unroll
        for (int r = 0; r < 4; r++)
            Zout[(nt * 16 + l15) * 65 + m0 + quad * 4 + r] = Zo[nt][r];
    __syncthreads();
    {
        int pl = t & 63;
        int q = qb + pl;
        if (q < Q) {
            #pragma unroll
            for (int it = 0; it < 32; it++) {
                int n = it * 4 + (t >> 6);
                out[n * Q + q] = Zout[n * 65 + pl];
            }
        }
    }
}

extern "C" void kernel_launch(void* const* d_in, const int* in_sizes, int n_in,
                              void* d_out, int out_size, void* d_ws, size_t ws_size,
                              hipStream_t stream) {
    (void)in_sizes; (void)n_in; (void)out_size; (void)ws_size;
    const float* q      = (const float*)d_in[0];
    const float* k      = (const float*)d_in[1];
    const float* v      = (const float*)d_in[2];
    const float* Wl     = (const float*)d_in[3];
    const int*   vis    = (const int*)  d_in[4];
    const float* skip   = (const float*)d_in[5];
    const float* qn_w   = (const float*)d_in[6];
    const float* qn_b   = (const float*)d_in[7];
    const float* kn_w   = (const float*)d_in[8];
    const float* kn_b   = (const float*)d_in[9];
    const float* vn_w   = (const float*)d_in[10];
    const float* vn_b   = (const float*)d_in[11];
    const float* pre_w  = (const float*)d_in[12];
    const float* pre_b  = (const float*)d_in[13];
    const float* post_w = (const float*)d_in[14];
    const float* post_b = (const float*)d_in[15];
    const float* wq     = (const float*)d_in[16];
    const float* bq     = (const float*)d_in[17];
    const float* wk     = (const float*)d_in[18];
    const float* bk     = (const float*)d_in[19];
    const float* wv     = (const float*)d_in[20];
    const float* bv     = (const float*)d_in[21];
    const float* wp     = (const float*)d_in[22];
    const float* bp     = (const float*)d_in[23];
    const float* w1     = (const float*)d_in[24];
    const float* b1     = (const float*)d_in[25];
    const float* w2     = (const float*)d_in[26];
    const float* b2     = (const float*)d_in[27];
    float* out = (float*)d_out;

    char* ws = (char*)d_ws;
    unsigned short* xq  = (unsigned short*)(ws + 0);          //  2560*128 bf16
    unsigned short* xk  = (unsigned short*)(ws + 655360);     // 10112*128 bf16
    unsigned short* xv  = (unsigned short*)(ws + 3244032);
    unsigned short* qh  = (unsigned short*)(ws + 5832704);
    unsigned short* kh  = (unsigned short*)(ws + 6488064);
    unsigned short* vhT = (unsigned short*)(ws + 9076736);    // [128][10112] bf16
    unsigned short* wqT = (unsigned short*)(ws + 11665408);
    unsigned short* wkT = (unsigned short*)(ws + 11698176);
    unsigned short* wvT = (unsigned short*)(ws + 11730944);
    unsigned short* wpT = (unsigned short*)(ws + 11763712);
    unsigned short* w1T = (unsigned short*)(ws + 11796480);
    unsigned short* w2T = (unsigned short*)(ws + 11862016);
    unsigned* OpartU    = (unsigned*)(ws + 11927552);         // 21*OPS u32 (padded stride)
    float* lpart        = (float*)(ws + 25695488);            // 21*LPS f32 (padded stride)
    float* linv         = (float*)(ws + 26561024);            // 2560*4 f32
    unsigned* A1u       = (unsigned*)(ws + 655360);           // overlays dead xk (2560*64 u32)
    // high-water: ~26.6 MB

    wcvt_kernel<<<dim3(512), dim3(256), 0, stream>>>(wq, wk, wv, wp, w1, w2,
                                                     wqT, wkT, wvT, wpT, w1T, w2T);
    ln_kernel<<<dim3(1417), dim3(256), 0, stream>>>(q, k, v, qn_w, qn_b, kn_w, kn_b, vn_w, vn_b,
                                                    xq, xk, xv);
    proj_kernel<<<dim3(356), dim3(256), 0, stream>>>(xq, xk, xv, wqT, wkT, wvT, bq, bk, bv,
                                                     qh, kh, vhT);
    attn_kernel<<<dim3(40 * SPLITS), dim3(256), 0, stream>>>(qh, kh, vhT, Wl, vis, OpartU, lpart);
    linv_kernel<<<dim3(40), dim3(256), 0, stream>>>(lpart, linv);
    combine_kernel<<<dim3(640), dim3(256), 0, stream>>>(OpartU, linv, A1u);
    mlp_kernel<<<dim3(40), dim3(256), 0, stream>>>((const unsigned short*)A1u, wpT, bp, skip,
                                                   pre_w, pre_b, w1T, b1, w2T, b2,
                                                   post_w, post_b, out);
}

// Round 6
// 365.661 us; speedup vs baseline: 1.2223x; 1.2223x over previous
//
#include <hip/hip_runtime.h>
#include <hip/hip_bf16.h>
#include <math.h>

typedef short short8 __attribute__((ext_vector_type(8)));
typedef float floatx4 __attribute__((ext_vector_type(4)));
typedef int   intx4  __attribute__((ext_vector_type(4)));

#define D 128
#define Q 2500
#define QPAD 2560
#define NK 10080
#define NKPAD 10112
#define SPLITS 35
#define CPS 9   // 35*9*32 = 10080
// padded strides (avoid 4096B channel alignment)
#define OPS 163904   // u32 per split for OpartU
#define LPS 10304    // f32 per split for lpart
// 1/sqrt(32) * log2(e)
#define QSCALE 0.25501268426834347f
#define NEGBIG -3.0e38f

__device__ __forceinline__ unsigned short f2bf(float f) {
    unsigned u = __float_as_uint(f);
    unsigned r = (u + 0x7fffu + ((u >> 16) & 1u)) >> 16;
    return (unsigned short)r;
}
__device__ __forceinline__ unsigned pack2bf(float lo, float hi) {
    unsigned u0 = __float_as_uint(lo) + 0x8000u;
    unsigned u1 = __float_as_uint(hi) + 0x8000u;
    return (u0 >> 16) | (u1 & 0xffff0000u);
}
__device__ __forceinline__ float bflo(unsigned u) { return __uint_as_float(u << 16); }
__device__ __forceinline__ float bfhi(unsigned u) { return __uint_as_float(u & 0xffff0000u); }

// ---------- prep: LayerNorm (32-pos tiles, full-line reads) + weight convert ----------
__global__ __launch_bounds__(256) void prep_kernel(
    const float* __restrict__ qi, const float* __restrict__ ki, const float* __restrict__ vi,
    const float* __restrict__ qw, const float* __restrict__ qb_,
    const float* __restrict__ kw, const float* __restrict__ kb,
    const float* __restrict__ vw, const float* __restrict__ vb,
    unsigned short* __restrict__ xq, unsigned short* __restrict__ xk,
    unsigned short* __restrict__ xv,
    const float* __restrict__ wq, const float* __restrict__ wk,
    const float* __restrict__ wv, const float* __restrict__ wp,
    const float* __restrict__ w1, const float* __restrict__ w2,
    unsigned short* __restrict__ wqT, unsigned short* __restrict__ wkT,
    unsigned short* __restrict__ wvT, unsigned short* __restrict__ wpT,
    unsigned short* __restrict__ w1T, unsigned short* __restrict__ w2T) {
    int bid = blockIdx.x, t = threadIdx.x;
    if (bid >= 715) {
        int idx = (bid - 715) * 256 + t;  // 131072 total
        if (idx < 49152) {
            int m = idx >> 14;
            int local = idx & 16383;
            int n = local >> 7, kk = local & 127;
            const float* w = (m == 0) ? wq : ((m == 1) ? wk : wv);
            unsigned short* o = (m == 0) ? wqT : ((m == 1) ? wkT : wvT);
            o[local] = f2bf(w[kk * 128 + n]);
        } else if (idx < 65536) {
            int local = idx - 49152;
            int n = local >> 7, kk = local & 127;
            wpT[local] = f2bf(wp[kk * 128 + n]);
        } else if (idx < 98304) {
            int local = idx - 65536;
            int n = local >> 7, kk = local & 127;
            w1T[local] = f2bf(w1[kk * 256 + n]);
        } else {
            int local = idx - 98304;
            int n = local >> 8, kk = local & 255;
            w2T[local] = f2bf(w2[kk * 128 + n]);
        }
        return;
    }
    __shared__ float lds2[32 * 132];
    const float* src; unsigned short* dst; const float *g, *b;
    int S, valid;
    if (bid < 79) {
        int p0 = bid * 32;
        src = qi + p0; S = Q; dst = xq + p0 * D; g = qw; b = qb_;
        valid = Q - p0; if (valid > 32) valid = 32;
    } else if (bid < 397) {
        int tt = bid - 79;
        int n = tt / 53, tile = tt - n * 53, r = tile * 32;
        src = ki + (size_t)(n * 128) * 1680 + r; S = 1680;
        dst = xk + (n * 1680 + r) * D; g = kw; b = kb;
        valid = 1680 - r; if (valid > 32) valid = 32;
    } else {
        int tt = bid - 397;
        int n = tt / 53, tile = tt - n * 53, r = tile * 32;
        src = vi + (size_t)(n * 128) * 1680 + r; S = 1680;
        dst = xv + (n * 1680 + r) * D; g = vw; b = vb;
        valid = 1680 - r; if (valid > 32) valid = 32;
    }
    #pragma unroll
    for (int pass = 0; pass < 4; pass++) {
        int s = pass * 256 + t;
        int d = s >> 3, ps = s & 7;
        floatx4 val = {0.f, 0.f, 0.f, 0.f};
        if (ps * 4 < valid) val = *(const floatx4*)(src + (size_t)d * S + ps * 4);
        #pragma unroll
        for (int j = 0; j < 4; j++) lds2[(ps * 4 + j) * 132 + d] = val[j];
    }
    __syncthreads();
    int lane = t & 63, wvx = t >> 6;
    int pos = wvx * 8 + (lane >> 3), l7 = lane & 7;
    floatx4 x4[4];
    #pragma unroll
    for (int k = 0; k < 4; k++) x4[k] = *(const floatx4*)(&lds2[pos * 132 + l7 * 16 + k * 4]);
    float s = 0.f, ss = 0.f;
    #pragma unroll
    for (int k = 0; k < 4; k++)
        #pragma unroll
        for (int j = 0; j < 4; j++) { s += x4[k][j]; ss += x4[k][j] * x4[k][j]; }
    #pragma unroll
    for (int m = 1; m <= 4; m <<= 1) { s += __shfl_xor(s, m, 64); ss += __shfl_xor(ss, m, 64); }
    float mean = s * (1.0f / 128.0f);
    float var = ss * (1.0f / 128.0f) - mean * mean;
    float rstd = rsqrtf(var + 1e-5f);
    short8 o1, o2;
    #pragma unroll
    for (int k = 0; k < 4; k++) {
        floatx4 g4 = *(const floatx4*)(g + l7 * 16 + k * 4);
        floatx4 b4 = *(const floatx4*)(b + l7 * 16 + k * 4);
        #pragma unroll
        for (int j = 0; j < 4; j++) {
            float o = (x4[k][j] - mean) * rstd * g4[j] + b4[j];
            if (k < 2) o1[k * 4 + j] = (short)f2bf(o);
            else o2[(k - 2) * 4 + j] = (short)f2bf(o);
        }
    }
    if (pos < valid) {
        *(short8*)(dst + pos * D + l7 * 16) = o1;
        *(short8*)(dst + pos * D + l7 * 16 + 8) = o2;
    }
}

// ---------- Projection GEMM, vectorized weights; V written transposed ----------
__global__ __launch_bounds__(256) void proj_kernel(
    const unsigned short* __restrict__ xq, const unsigned short* __restrict__ xk,
    const unsigned short* __restrict__ xv,
    const unsigned short* __restrict__ wqT, const unsigned short* __restrict__ wkT,
    const unsigned short* __restrict__ wvT,
    const float* __restrict__ bq, const float* __restrict__ bk, const float* __restrict__ bv,
    unsigned short* __restrict__ qh, unsigned short* __restrict__ kh,
    unsigned short* __restrict__ vhT) {
    __shared__ short vlds[128 * 72];
    int bid = blockIdx.x;
    const unsigned short *src, *wT; const float* bias; int mb, mode; float scale;
    if (bid < 40)       { mode = 0; src = xq; wT = wqT; bias = bq; mb = bid * 64; scale = QSCALE; }
    else if (bid < 198) { mode = 1; src = xk; wT = wkT; bias = bk; mb = (bid - 40) * 64; scale = 1.0f; }
    else                { mode = 2; src = xv; wT = wvT; bias = bv; mb = (bid - 198) * 64; scale = 1.0f; }
    int t = threadIdx.x, wave = t >> 6, lane = t & 63;
    int l15 = lane & 15, quad = lane >> 4;
    int m0 = mb + wave * 16;
    floatx4 acc[8];
    #pragma unroll
    for (int i = 0; i < 8; i++) acc[i] = (floatx4){0.f, 0.f, 0.f, 0.f};
    #pragma unroll
    for (int kf = 0; kf < 4; kf++) {
        short8 A = *(const short8*)(src + (m0 + l15) * D + kf * 32 + quad * 8);
        #pragma unroll
        for (int nt = 0; nt < 8; nt++) {
            short8 Bv = *(const short8*)(wT + (nt * 16 + l15) * D + kf * 32 + quad * 8);
            acc[nt] = __builtin_amdgcn_mfma_f32_16x16x32_bf16(A, Bv, acc[nt], 0, 0, 0);
        }
    }
    if (mode != 2) {
        unsigned short* dst = (mode == 0) ? qh : kh;
        #pragma unroll
        for (int nt = 0; nt < 8; nt++) {
            float bb = bias[nt * 16 + l15];
            #pragma unroll
            for (int r = 0; r < 4; r++)
                dst[(m0 + quad * 4 + r) * D + nt * 16 + l15] = f2bf((acc[nt][r] + bb) * scale);
        }
    } else {
        #pragma unroll
        for (int nt = 0; nt < 8; nt++) {
            float bb = bias[nt * 16 + l15];
            #pragma unroll
            for (int r = 0; r < 4; r++)
                vlds[(nt * 16 + l15) * 72 + (wave * 16 + quad * 4 + r)] =
                    (short)f2bf(acc[nt][r] + bb);
        }
        __syncthreads();
        int pr = t & 31, dd = t >> 5;
        int sub = pr >> 4, i = pr & 15;
        #pragma unroll
        for (int pass = 0; pass < 16; pass++) {
            int d = pass * 8 + dd;
            unsigned lo = (unsigned short)vlds[d * 72 + sub * 32 + i];
            unsigned hi = (unsigned short)vlds[d * 72 + sub * 32 + 16 + i];
            *(unsigned*)(vhT + (size_t)d * NKPAD + mb + sub * 32 + 2 * i) = lo | (hi << 16);
        }
    }
}

// ---------- Fused attention v5: block-shared double-buffered K/V LDS staging ----------
__global__ __launch_bounds__(256, 3) void attn_kernel(
    const unsigned short* __restrict__ qh, const unsigned short* __restrict__ kh,
    const unsigned short* __restrict__ vhT,
    const float* __restrict__ Wl, const int* __restrict__ vis,
    unsigned* __restrict__ OpartU, float* __restrict__ lpart) {
    __shared__ short Kl[2][32 * 136];   // K chunk [k][d] pad 136
    __shared__ short Vl[2][128 * 48];   // V^T chunk [d][k] pad 48
    __shared__ unsigned Pl[4][16 * 18]; // per-wave P transform [k-pair][q] pad 18
    int bid = blockIdx.x;
    int split = bid % SPLITS, qt = bid / SPLITS;
    int t = threadIdx.x, wave = t >> 6, lane = t & 63;
    int l15 = lane & 15, quad = lane >> 4;
    int qb = qt * 64 + wave * 16;
    int k00 = split * (CPS * 32);

    // Q fragments (loop-invariant), B-operand layout
    short8 qB[4];
    #pragma unroll
    for (int h = 0; h < 4; h++)
        qB[h] = *(const short8*)(qh + (size_t)(qb + l15) * D + h * 32 + quad * 8);

    // staging assignment: K: thread -> row kr, 2x16B segs; V: row vd, 2x16B segs
    int kr = t >> 3, ks = (t & 7) * 2;
    int vd = t >> 1, vs = (t & 1) * 2;
    const uint4* ksrc = (const uint4*)(kh + (size_t)(k00 + kr) * D + ks * 8);
    const uint4* vsrc = (const uint4*)(vhT + (size_t)vd * NKPAD + k00 + vs * 8);
    short* kdst = &Kl[0][kr * 136 + ks * 8];
    short* vdst = &Vl[0][vd * 48 + vs * 8];

    // W/vis per lane: q = qb+l15, k = quad*4..+3 (+16)
    int wrow = qb + l15; if (wrow >= Q) wrow = Q - 1;
    const float* wp = Wl + (size_t)wrow * NK + k00 + quad * 4;
    const int*   vp = vis + (size_t)wrow * NK + k00 + quad * 4;

    const floatx4 zf = {0.f, 0.f, 0.f, 0.f};
    floatx4 O[4][2];
    float lacc[4];
    #pragma unroll
    for (int h = 0; h < 4; h++) { O[h][0] = zf; O[h][1] = zf; lacc[h] = 0.f; }

    // prologue: chunk 0
    uint4 ka = ksrc[0], kb2 = ksrc[1];
    uint4 va = vsrc[0], vb2 = vsrc[1];
    floatx4 wc0 = *(const floatx4*)wp;
    floatx4 wc1 = *(const floatx4*)(wp + 16);
    intx4 vc0 = *(const intx4*)vp;
    intx4 vc1 = *(const intx4*)(vp + 16);
    *(uint4*)kdst = ka;       *(uint4*)(kdst + 8) = kb2;
    *(uint4*)vdst = va;       *(uint4*)(vdst + 8) = vb2;

    unsigned* pw = Pl[wave];
    #pragma unroll 1
    for (int c = 0; c < CPS; c++) {
        __syncthreads();
        int buf = c & 1;
        uint4 nka, nkb, nva, nvb;
        floatx4 wn0, wn1; intx4 vn0, vn1;
        if (c + 1 < CPS) {
            const uint4* ks2 = ksrc + (size_t)(c + 1) * 512;
            const uint4* vs2 = vsrc + (size_t)(c + 1) * 4;
            nka = ks2[0]; nkb = ks2[1];
            nva = vs2[0]; nvb = vs2[1];
            wn0 = *(const floatx4*)(wp + (c + 1) * 32);
            wn1 = *(const floatx4*)(wp + (c + 1) * 32 + 16);
            vn0 = *(const intx4*)(vp + (c + 1) * 32);
            vn1 = *(const intx4*)(vp + (c + 1) * 32 + 16);
        }
        float a2[8], b2[8];
        #pragma unroll
        for (int r = 0; r < 4; r++) {
            a2[r]     = vc0[r] ? wc0[r] : 0.f;
            b2[r]     = vc0[r] ? 0.f : wc0[r] * NEGBIG;
            a2[4 + r] = vc1[r] ? wc1[r] : 0.f;
            b2[4 + r] = vc1[r] ? 0.f : wc1[r] * NEGBIG;
        }
        const short* Kb = Kl[buf];
        const short* Vb = Vl[buf];
        #pragma unroll
        for (int h = 0; h < 4; h++) {
            short8 kA0 = *(const short8*)(Kb + l15 * 136 + h * 32 + quad * 8);
            short8 kA1 = *(const short8*)(Kb + (16 + l15) * 136 + h * 32 + quad * 8);
            floatx4 S0 = __builtin_amdgcn_mfma_f32_16x16x32_bf16(kA0, qB[h], zf, 0, 0, 0);
            floatx4 S1 = __builtin_amdgcn_mfma_f32_16x16x32_bf16(kA1, qB[h], zf, 0, 0, 0);
            float p0[4], p1[4];
            #pragma unroll
            for (int r = 0; r < 4; r++) {
                p0[r] = exp2f(S0[r] * a2[r] + b2[r]);
                p1[r] = exp2f(S1[r] * a2[4 + r] + b2[4 + r]);
                lacc[h] += p0[r] + p1[r];
            }
            // P^T C->B via per-wave LDS (in-order DS within wave)
            pw[(quad * 2) * 18 + l15]     = pack2bf(p0[0], p0[1]);
            pw[(quad * 2 + 1) * 18 + l15] = pack2bf(p0[2], p0[3]);
            pw[(8 + quad * 2) * 18 + l15]     = pack2bf(p1[0], p1[1]);
            pw[(8 + quad * 2 + 1) * 18 + l15] = pack2bf(p1[2], p1[3]);
            union { unsigned u[4]; short8 s8; } pb;
            #pragma unroll
            for (int jj = 0; jj < 4; jj++)
                pb.u[jj] = pw[(quad * 4 + jj) * 18 + l15];
            short8 vA0 = *(const short8*)(Vb + (h * 32 + l15) * 48 + quad * 8);
            short8 vA1 = *(const short8*)(Vb + (h * 32 + 16 + l15) * 48 + quad * 8);
            O[h][0] = __builtin_amdgcn_mfma_f32_16x16x32_bf16(vA0, pb.s8, O[h][0], 0, 0, 0);
            O[h][1] = __builtin_amdgcn_mfma_f32_16x16x32_bf16(vA1, pb.s8, O[h][1], 0, 0, 0);
        }
        if (c + 1 < CPS) {
            short* kd = buf ? kdst : (kdst + 32 * 136);
            short* vd2 = buf ? vdst : (vdst + 128 * 48);
            *(uint4*)kd = nka;       *(uint4*)(kd + 8) = nkb;
            *(uint4*)vd2 = nva;      *(uint4*)(vd2 + 8) = nvb;
            wc0 = wn0; wc1 = wn1; vc0 = vn0; vc1 = vn1;
        }
    }

    int row = qb + l15;
    #pragma unroll
    for (int h = 0; h < 4; h++) {
        float lv = lacc[h];
        lv += __shfl_xor(lv, 16, 64);
        lv += __shfl_xor(lv, 32, 64);
        if (quad == 0) lpart[(size_t)split * LPS + row * 4 + h] = lv;
        #pragma unroll
        for (int tl = 0; tl < 2; tl++) {
            uint2 o2;
            o2.x = pack2bf(O[h][tl][0], O[h][tl][1]);
            o2.y = pack2bf(O[h][tl][2], O[h][tl][3]);
            *(uint2*)(OpartU + (size_t)split * OPS + ((size_t)row * 4 + h) * 16 + tl * 8 + quad * 2) = o2;
        }
    }
}

// ---------- MLP epilogue with inline split-combine ----------
__global__ __launch_bounds__(256) void mlp_kernel(
    const unsigned* __restrict__ Opart, const float* __restrict__ lpart,
    const unsigned short* __restrict__ wpT,
    const float* __restrict__ bp, const float* __restrict__ skip,
    const float* __restrict__ pre_w, const float* __restrict__ pre_b,
    const unsigned short* __restrict__ w1T, const float* __restrict__ b1,
    const unsigned short* __restrict__ w2T, const float* __restrict__ b2,
    const float* __restrict__ post_w, const float* __restrict__ post_b,
    float* __restrict__ out) {
    __shared__ __align__(16) char smem[68608];
    short* A1l = (short*)smem;             // [64][136] bf16
    short* Z1 = (short*)(smem + 17408);    // [64][136]
    short* H1 = (short*)(smem + 34816);    // [64][264]
    float* Zout = (float*)(smem + 17408);  // [128][65] overlay after barrier
    unsigned* A1u = (unsigned*)smem;

    int qb = blockIdx.x * 64;
    int t = threadIdx.x, wave = t >> 6, lane = t & 63;
    int l15 = lane & 15, quad = lane >> 4;
    int m0 = wave * 16;

    // inline combine: thread -> (row = t>>2, head = t&3), 16 u32 slots
    {
        int row = t >> 2, he = t & 3;
        int grow = qb + row;
        float lsum = 0.f;
        #pragma unroll 5
        for (int sp = 0; sp < SPLITS; sp++) lsum += lpart[(size_t)sp * LPS + grow * 4 + he];
        float inv = 1.0f / fmaxf(lsum, 1e-30f);
        size_t base = ((size_t)grow * 4 + he) * 16;
        #pragma unroll
        for (int sl = 0; sl < 4; sl++) {
            float a0 = 0.f, a1 = 0.f, a2 = 0.f, a3 = 0.f, a4 = 0.f, a5 = 0.f, a6 = 0.f, a7 = 0.f;
            #pragma unroll 5
            for (int sp = 0; sp < SPLITS; sp++) {
                uint4 u = *(const uint4*)(Opart + (size_t)sp * OPS + base + sl * 4);
                a0 += bflo(u.x); a1 += bfhi(u.x);
                a2 += bflo(u.y); a3 += bfhi(u.y);
                a4 += bflo(u.z); a5 += bfhi(u.z);
                a6 += bflo(u.w); a7 += bfhi(u.w);
            }
            int o = row * 68 + he * 16 + sl * 4;
            A1u[o + 0] = pack2bf(a0 * inv, a1 * inv);
            A1u[o + 1] = pack2bf(a2 * inv, a3 * inv);
            A1u[o + 2] = pack2bf(a4 * inv, a5 * inv);
            A1u[o + 3] = pack2bf(a6 * inv, a7 * inv);
        }
    }
    __syncthreads();

    // G1: Z = A1 @ wp
    floatx4 z[8];
    #pragma unroll
    for (int i = 0; i < 8; i++) z[i] = (floatx4){0.f, 0.f, 0.f, 0.f};
    #pragma unroll
    for (int kf = 0; kf < 4; kf++) {
        short8 A = *(const short8*)(A1l + (m0 + l15) * 136 + kf * 32 + quad * 8);
        #pragma unroll
        for (int nt = 0; nt < 8; nt++) {
            short8 Bv = *(const short8*)(wpT + (nt * 16 + l15) * D + kf * 32 + quad * 8);
            z[nt] = __builtin_amdgcn_mfma_f32_16x16x32_bf16(A, Bv, z[nt], 0, 0, 0);
        }
    }
    float Zv[8][4];
    #pragma unroll
    for (int nt = 0; nt < 8; nt++) {
        int n = nt * 16 + l15;
        float bb = bp[n];
        #pragma unroll
        for (int r = 0; r < 4; r++) {
            int q = qb + m0 + quad * 4 + r;
            int qc = q < Q ? q : (Q - 1);
            Zv[nt][r] = z[nt][r] + bb + skip[n * Q + qc];
        }
    }
    // pre-LN
    float Zn[8][4];
    {
        #pragma unroll
        for (int r = 0; r < 4; r++) {
            float s1 = 0.f, s2 = 0.f;
            #pragma unroll
            for (int nt = 0; nt < 8; nt++) { s1 += Zv[nt][r]; s2 += Zv[nt][r] * Zv[nt][r]; }
            #pragma unroll
            for (int m = 1; m <= 8; m <<= 1) { s1 += __shfl_xor(s1, m, 64); s2 += __shfl_xor(s2, m, 64); }
            float mean = s1 * (1.0f / 128.0f);
            float var = s2 * (1.0f / 128.0f) - mean * mean;
            float rstd = rsqrtf(var + 1e-5f);
            #pragma unroll
            for (int nt = 0; nt < 8; nt++) Zn[nt][r] = (Zv[nt][r] - mean) * rstd;
        }
        #pragma unroll
        for (int nt = 0; nt < 8; nt++) {
            int n = nt * 16 + l15;
            float g = pre_w[n], be = pre_b[n];
            #pragma unroll
            for (int r = 0; r < 4; r++) {
                Zn[nt][r] = Zn[nt][r] * g + be;
                Z1[(m0 + quad * 4 + r) * 136 + n] = (short)f2bf(Zn[nt][r]);
            }
        }
    }
    // G2: H = gelu(Z1 @ w1 + b1)
    {
        floatx4 h2[16];
        #pragma unroll
        for (int i = 0; i < 16; i++) h2[i] = (floatx4){0.f, 0.f, 0.f, 0.f};
        #pragma unroll
        for (int kf = 0; kf < 4; kf++) {
            short8 A = *(const short8*)(Z1 + (m0 + l15) * 136 + kf * 32 + quad * 8);
            #pragma unroll
            for (int nt = 0; nt < 16; nt++) {
                short8 Bv = *(const short8*)(w1T + (nt * 16 + l15) * D + kf * 32 + quad * 8);
                h2[nt] = __builtin_amdgcn_mfma_f32_16x16x32_bf16(A, Bv, h2[nt], 0, 0, 0);
            }
        }
        #pragma unroll
        for (int nt = 0; nt < 16; nt++) {
            int n = nt * 16 + l15;
            float bb = b1[n];
            #pragma unroll
            for (int r = 0; r < 4; r++) {
                float x = h2[nt][r] + bb;
                float gl = 0.5f * x * (1.0f + erff(x * 0.70710678118654752f));
                H1[(m0 + quad * 4 + r) * 264 + n] = (short)f2bf(gl);
            }
        }
    }
    // G3: R = H1 @ w2 + b2; Z2 = Zn + R
    floatx4 o3[8];
    #pragma unroll
    for (int i = 0; i < 8; i++) o3[i] = (floatx4){0.f, 0.f, 0.f, 0.f};
    #pragma unroll
    for (int kf = 0; kf < 8; kf++) {
        short8 A = *(const short8*)(H1 + (m0 + l15) * 264 + kf * 32 + quad * 8);
        #pragma unroll
        for (int nt = 0; nt < 8; nt++) {
            short8 Bv = *(const short8*)(w2T + (nt * 16 + l15) * 256 + kf * 32 + quad * 8);
            o3[nt] = __builtin_amdgcn_mfma_f32_16x16x32_bf16(A, Bv, o3[nt], 0, 0, 0);
        }
    }
    float Z2[8][4];
    #pragma unroll
    for (int nt = 0; nt < 8; nt++) {
        int n = nt * 16 + l15;
        float bb = b2[n];
        #pragma unroll
        for (int r = 0; r < 4; r++) Z2[nt][r] = Zn[nt][r] + o3[nt][r] + bb;
    }
    // post-LN
    float Zo[8][4];
    {
        #pragma unroll
        for (int r = 0; r < 4; r++) {
            float s1 = 0.f, s2 = 0.f;
            #pragma unroll
            for (int nt = 0; nt < 8; nt++) { s1 += Z2[nt][r]; s2 += Z2[nt][r] * Z2[nt][r]; }
            #pragma unroll
            for (int m = 1; m <= 8; m <<= 1) { s1 += __shfl_xor(s1, m, 64); s2 += __shfl_xor(s2, m, 64); }
            float mean = s1 * (1.0f / 128.0f);
            float var = s2 * (1.0f / 128.0f) - mean * mean;
            float rstd = rsqrtf(var + 1e-5f);
            #pragma unroll
            for (int nt = 0; nt < 8; nt++) Zo[nt][r] = (Z2[nt][r] - mean) * rstd;
        }
        #pragma unroll
        for (int nt = 0; nt < 8; nt++) {
            int n = nt * 16 + l15;
            float g = post_w[n], be = post_b[n];
            #pragma unroll
            for (int r = 0; r < 4; r++) Zo[nt][r] = Zo[nt][r] * g + be;
        }
    }
    __syncthreads();
    #pragma unroll
    for (int nt = 0; nt < 8; nt++)
        #pragma unroll
        for (int r = 0; r < 4; r++)
            Zout[(nt * 16 + l15) * 65 + m0 + quad * 4 + r] = Zo[nt][r];
    __syncthreads();
    {
        int pl = t & 63;
        int q = qb + pl;
        if (q < Q) {
            #pragma unroll
            for (int it = 0; it < 32; it++) {
                int n = it * 4 + (t >> 6);
                out[n * Q + q] = Zout[n * 65 + pl];
            }
        }
    }
}

extern "C" void kernel_launch(void* const* d_in, const int* in_sizes, int n_in,
                              void* d_out, int out_size, void* d_ws, size_t ws_size,
                              hipStream_t stream) {
    (void)in_sizes; (void)n_in; (void)out_size; (void)ws_size;
    const float* q      = (const float*)d_in[0];
    const float* k      = (const float*)d_in[1];
    const float* v      = (const float*)d_in[2];
    const float* Wl     = (const float*)d_in[3];
    const int*   vis    = (const int*)  d_in[4];
    const float* skip   = (const float*)d_in[5];
    const float* qn_w   = (const float*)d_in[6];
    const float* qn_b   = (const float*)d_in[7];
    const float* kn_w   = (const float*)d_in[8];
    const float* kn_b   = (const float*)d_in[9];
    const float* vn_w   = (const float*)d_in[10];
    const float* vn_b   = (const float*)d_in[11];
    const float* pre_w  = (const float*)d_in[12];
    const float* pre_b  = (const float*)d_in[13];
    const float* post_w = (const float*)d_in[14];
    const float* post_b = (const float*)d_in[15];
    const float* wq     = (const float*)d_in[16];
    const float* bq     = (const float*)d_in[17];
    const float* wk     = (const float*)d_in[18];
    const float* bk     = (const float*)d_in[19];
    const float* wv     = (const float*)d_in[20];
    const float* bv     = (const float*)d_in[21];
    const float* wp     = (const float*)d_in[22];
    const float* bp     = (const float*)d_in[23];
    const float* w1     = (const float*)d_in[24];
    const float* b1     = (const float*)d_in[25];
    const float* w2     = (const float*)d_in[26];
    const float* b2     = (const float*)d_in[27];
    float* out = (float*)d_out;

    char* ws = (char*)d_ws;
    unsigned short* xq  = (unsigned short*)(ws + 0);          //  2560*128 bf16
    unsigned short* xk  = (unsigned short*)(ws + 655360);     // 10112*128 bf16
    unsigned short* xv  = (unsigned short*)(ws + 3244032);
    unsigned short* qh  = (unsigned short*)(ws + 5832704);
    unsigned short* kh  = (unsigned short*)(ws + 6488064);
    unsigned short* vhT = (unsigned short*)(ws + 9076736);    // [128][10112] bf16
    unsigned short* wqT = (unsigned short*)(ws + 11665408);
    unsigned short* wkT = (unsigned short*)(ws + 11698176);
    unsigned short* wvT = (unsigned short*)(ws + 11730944);
    unsigned short* wpT = (unsigned short*)(ws + 11763712);
    unsigned short* w1T = (unsigned short*)(ws + 11796480);
    unsigned short* w2T = (unsigned short*)(ws + 11862016);
    unsigned* OpartU    = (unsigned*)(ws + 11927552);         // 35*OPS u32 (padded stride)
    float* lpart        = (float*)(ws + 34874112);            // 35*LPS f32 (padded stride)
    // high-water: ~36.3 MB

    prep_kernel<<<dim3(1227), dim3(256), 0, stream>>>(
        q, k, v, qn_w, qn_b, kn_w, kn_b, vn_w, vn_b, xq, xk, xv,
        wq, wk, wv, wp, w1, w2, wqT, wkT, wvT, wpT, w1T, w2T);
    proj_kernel<<<dim3(356), dim3(256), 0, stream>>>(xq, xk, xv, wqT, wkT, wvT, bq, bk, bv,
                                                     qh, kh, vhT);
    attn_kernel<<<dim3(40 * SPLITS), dim3(256), 0, stream>>>(qh, kh, vhT, Wl, vis, OpartU, lpart);
    mlp_kernel<<<dim3(40), dim3(256), 0, stream>>>(OpartU, lpart, wpT, bp, skip,
                                                   pre_w, pre_b, w1T, b1, w2T, b2,
                                                   post_w, post_b, out);
}